// Round 17
// baseline (293.973 us; speedup 1.0000x reference)
//
#include <hip/hip_runtime.h>

#define NN 20000
#define NNP 20096       // padded rows: 314*64
#define NEIGH 12
#define NCRYS 20
#define NSUB 16         // pooled partial-sum split

typedef __bf16 bf16x8 __attribute__((ext_vector_type(8)));
typedef __bf16 bf16x4 __attribute__((ext_vector_type(4)));
typedef __bf16 bf16x2 __attribute__((ext_vector_type(2)));
typedef float f32x4 __attribute__((ext_vector_type(4)));

__device__ __forceinline__ float readlane_f(float v, int l) {
    return __int_as_float(__builtin_amdgcn_readlane(__float_as_int(v), l));
}

// ============================================================
// pack8: one thread -> one contiguous bf16x8 chunk of Wp (8 k's, one n).
// Writes fully coalesced. Layer-1 layout (N=256): Wp[kt][nt][k8][ni][j]
// ============================================================
__device__ __forceinline__ void pack8(const float* Wrel, const float* Wroot,
                                      __bf16* Wp, int K, int t) {
    int n = t & 255, kq = t >> 8;          // kq = kt*4 + k8
    int kt = kq >> 2, k8 = kq & 3;
    int r = n >> 6, h = n & 63;
    int k0 = kt * 32 + k8 * 8;
    const float* src = (r < 3) ? (Wrel + ((size_t)r * K + k0) * 64 + h)
                               : (Wroot + (size_t)k0 * 64 + h);
    bf16x8 v;
#pragma unroll
    for (int j = 0; j < 8; ++j) v[j] = (__bf16)src[(size_t)j * 64];
    size_t off = (((((size_t)kt * 16 + (n >> 4)) * 4 + k8) * 16) + (n & 15)) * 8;
    *(bf16x8*)&Wp[off] = v;
}

// layer-2 concat (K=256, N=64): rows 0-63 W_root, 64+64q.. W_rel[q]
__device__ __forceinline__ void pack_cat8(const float* Wrel, const float* Wroot,
                                          __bf16* Wp, int t) {
    int n = t & 63, kq = t >> 6;           // kq = kt*4 + k8 (kt 0..7)
    int kt = kq >> 2, k8 = kq & 3;
    int k0 = kt * 32 + k8 * 8;             // 8-aligned, never crosses 64-block
    int q = k0 >> 6, kk = k0 & 63;
    const float* src = q ? (Wrel + (((size_t)(q - 1) * 64 + kk) * 64) + n)
                         : (Wroot + (size_t)kk * 64 + n);
    bf16x8 v;
#pragma unroll
    for (int j = 0; j < 8; ++j) v[j] = (__bf16)src[(size_t)j * 64];
    size_t off = (((((size_t)kt * 4 + (n >> 4)) * 4 + k8) * 16) + (n & 15)) * 8;
    *(bf16x8*)&Wp[off] = v;
}

// ============================================================
// setup: HEAVY-FIRST block order to trim the tail:
//   [0,628)    transpose (heaviest per block)
//   [628,884)  weight pack (medium)
//   [884,1822) adj build (light)
//   1822       pooled zero (replaces a memset dispatch)
// ============================================================
__global__ __launch_bounds__(256) void setup_kernel(
    const int* __restrict__ species, const int* __restrict__ nbr,
    int* __restrict__ adj, int* __restrict__ deg,
    const float* __restrict__ W1b_rel, const float* __restrict__ W1b_root,
    const float* __restrict__ W1a_rel, const float* __restrict__ W1a_root,
    const float* __restrict__ W2b_rel, const float* __restrict__ W2b_root,
    const float* __restrict__ W2a_rel, const float* __restrict__ W2a_root,
    __bf16* __restrict__ Wp1b, __bf16* __restrict__ Wp1a,
    __bf16* __restrict__ Wp2b, __bf16* __restrict__ Wp2a,
    const float* __restrict__ bond, const float* __restrict__ angle,
    float* __restrict__ bondT, float* __restrict__ angleT,
    float* __restrict__ pooled) {
    __shared__ float ls[64 * 145];
    const int bx = blockIdx.x, tid = threadIdx.x;
    if (bx < 628) {
        int tb = bx;
        if (tb < 314) {
            int m0 = tb * 64;
            for (int idx = tid; idx < 64 * 144; idx += 256) {
                int mm = idx / 144, j = idx - mm * 144;
                int m = m0 + mm;
                ls[mm * 145 + j] = (m < NN) ? angle[(size_t)m * 144 + j] : 0.f;
            }
            __syncthreads();
            for (int idx = tid; idx < 156 * 64; idx += 256) {
                int j = idx >> 6, mm = idx & 63;
                angleT[(size_t)j * NNP + m0 + mm] = (j < 144) ? ls[mm * 145 + j] : 0.f;
            }
        } else {
            int m0 = (tb - 314) * 64;
            for (int idx = tid; idx < 64 * 12; idx += 256) {
                int mm = idx / 12, j = idx - mm * 12;
                int m = m0 + mm;
                ls[mm * 13 + j] = (m < NN) ? bond[(size_t)m * 12 + j] : 0.f;
            }
            __syncthreads();
            for (int idx = tid; idx < 16 * 64; idx += 256) {
                int j = idx >> 6, mm = idx & 63;
                bondT[(size_t)j * NNP + m0 + mm] = (j < 12) ? ls[mm * 13 + j] : 0.f;
            }
        }
    } else if (bx < 884) {
        const int S0 = 15360;               // Wp1b pack8 (kt 0..14, K=480)
        const int S1 = S0 + 92160;          // Wp1a pack8 (kt 0..89, K=2880)
        const int S2 = S1 + 2048;           // Wp2b pack_cat8
        const int S3 = S2 + 2048;           // Wp2a pack_cat8
        const int S4 = S3 + 8192;           // Wp1b zero tail (k 480..511)
        const int S5 = S4 + 49152;          // Wp1a zero tail (k 2880..3071)
        for (int idx = (bx - 628) * 256 + tid; idx < S5; idx += 256 * 256) {
            if (idx < S0)       pack8(W1b_rel, W1b_root, Wp1b, 480, idx);
            else if (idx < S1)  pack8(W1a_rel, W1a_root, Wp1a, 2880, idx - S0);
            else if (idx < S2)  pack_cat8(W2b_rel, W2b_root, Wp2b, idx - S1);
            else if (idx < S3)  pack_cat8(W2a_rel, W2a_root, Wp2a, idx - S2);
            else if (idx < S4)  Wp1b[480 * 256 + (idx - S3)] = (__bf16)0.f;
            else                Wp1a[2880 * 256 + (idx - S4)] = (__bf16)0.f;
        }
    } else if (bx < 1822) {
        int e = (bx - 884) * 256 + tid;
        if (e < NN * NEIGH) {
            int i = e / NEIGH;
            int d = nbr[e];
            int r = species[i] + species[d];
            int slot = atomicAdd(&deg[d], 1);
            if (slot < 64) adj[(size_t)d * 64 + slot] = i | (r << 28);
        }
    } else {
        for (int i = tid; i < NCRYS * NSUB * 128; i += 256) pooled[i] = 0.f;
    }
}

// ============================================================
// gemm1: 64x256 tile, 512 threads (8 waves, each 64r x 32c, acc[4][2]).
// Proven R5 structure: 64-K phases in [ph0, ph0+nph), x2 unrolled loop,
// depth-2 B reg-prefetch, incremental pointers, LDS A ping-pong.
// Angle K-split x2: halves even/odd-interleaved in dispatch (partners
// share angleT read lines), outputs to SEPARATE bf16 planes.
// Bond blocks dispatched FIRST so the tail is uniform 24-phase blocks.
// ============================================================
template <int MODE>  // 0: bond KPAD=512 DIVN=40; 1: angle KPAD=3072 DIVN=20
__device__ __forceinline__ void gemm1_body(const float* __restrict__ xT,
                                           const __bf16* __restrict__ Wp,
                                           __bf16* __restrict__ Y, int mb,
                                           __bf16* __restrict__ Al,
                                           int ph0, int nph) {
    constexpr int DIVN = (MODE == 0) ? 40 : 20;
    constexpr int ADDJ = 64 / DIVN;          // 1 / 3
    constexpr int ADDS = 64 % DIVN;          // 24 / 4
    constexpr float F0 = (MODE == 0) ? 0.f : -1.f;
    constexpr float FS = (MODE == 0) ? (8.f / 39.f) : (2.f / 19.f);
    constexpr float NG2 = ((MODE == 0) ? -25.f : -100.f) * 1.44269504f;  // -gamma^-2*log2e
    const float C  = __builtin_amdgcn_exp2f(2.f * NG2 * FS * FS);
    const float P1 = NG2 * FS * FS;
    const float P2 = -2.f * NG2 * FS;

    const int tid = threadIdx.x;
    const int lane = tid & 63, wv = tid >> 6;
    const int m0 = mb * 64;
    const int smt = tid >> 7;             // 0..3
    const int sk8 = (tid >> 5) & 3;
    const int smi = (tid >> 1) & 15;
    const int sjh = (tid & 1) * 4;
    const int sgm = m0 + smt * 16 + smi;
    const int kk0 = sk8 * 8 + sjh;        // k-offset within 32-tile, 0..28
    const int swoff = (((smt * 4 + sk8) * 16 + smi) * 8 + sjh);
    const int k8b = lane >> 4, nib = lane & 15;

    f32x4 acc[4][2] = {};

    const int k00 = ph0 * 64 + kk0;
    const int k01 = ph0 * 64 + 32 + kk0;
    const float* pA0 = xT + (size_t)(k00 / DIVN) * NNP + sgm;
    const float* pA1 = xT + (size_t)(k01 / DIVN) * NNP + sgm;
    int sL0 = k00 % DIVN, sL1 = k01 % DIVN;
    int sS0 = sL0, sS1 = sL1;

    const bf16x8* pB0 = (const bf16x8*)Wp + (size_t)ph0 * 2048 +
                        ((size_t)(2 * wv) * 4 + k8b) * 16 + nib;
    const bf16x8* pB1 = pB0 + 1024;

    bf16x8 bEv[4], bOd[4];

    auto advL = [&]() {
        sL0 += ADDS;
        if (sL0 >= DIVN) { sL0 -= DIVN; pA0 += (size_t)(ADDJ + 1) * NNP; } else pA0 += (size_t)ADDJ * NNP;
        sL1 += ADDS;
        if (sL1 >= DIVN) { sL1 -= DIVN; pA1 += (size_t)(ADDJ + 1) * NNP; } else pA1 += (size_t)ADDJ * NNP;
    };
    auto advS = [&]() {
        sS0 += ADDS; if (sS0 >= DIVN) sS0 -= DIVN;
        sS1 += ADDS; if (sS1 >= DIVN) sS1 -= DIVN;
    };
    auto loadB = [&](bf16x8* d) {
        d[0] = pB0[0]; d[1] = pB0[64]; d[2] = pB1[0]; d[3] = pB1[64];
        pB0 += 2048; pB1 += 2048;
    };
    auto stage = [&](float a0, float a1, __bf16* dst) {
        float d0 = a0 - (F0 + (float)sS0 * FS);
        float d1 = a1 - (F0 + (float)sS1 * FS);
        float e0a = __builtin_amdgcn_exp2f(NG2 * d0 * d0);
        float q0a = __builtin_amdgcn_exp2f(fmaf(P2, d0, P1));
        float e0b = __builtin_amdgcn_exp2f(NG2 * d1 * d1);
        float q0b = __builtin_amdgcn_exp2f(fmaf(P2, d1, P1));
        float e1a = e0a * q0a, q1a = q0a * C;
        float e2a = e1a * q1a, e3a = e2a * q1a * C;
        float e1b = e0b * q0b, q1b = q0b * C;
        float e2b = e1b * q1b, e3b = e2b * q1b * C;
        bf16x4 v0, v1;
        v0[0] = (__bf16)e0a; v0[1] = (__bf16)e1a; v0[2] = (__bf16)e2a; v0[3] = (__bf16)e3a;
        v1[0] = (__bf16)e0b; v1[1] = (__bf16)e1b; v1[2] = (__bf16)e2b; v1[3] = (__bf16)e3b;
        *(bf16x4*)&dst[swoff] = v0;
        *(bf16x4*)&dst[2048 + swoff] = v1;
    };
    auto mma = [&](const __bf16* Ab, const bf16x8* bc) {
        bf16x8 af[4], ag[4];
#pragma unroll
        for (int t4 = 0; t4 < 4; ++t4) {
            af[t4] = *(const bf16x8*)&Ab[(((((t4 << 2) + k8b) << 4) + nib) << 3)];
            ag[t4] = *(const bf16x8*)&Ab[2048 + (((((t4 << 2) + k8b) << 4) + nib) << 3)];
        }
#pragma unroll
        for (int i = 0; i < 4; ++i) {
            acc[i][0] = __builtin_amdgcn_mfma_f32_16x16x32_bf16(af[i], bc[0], acc[i][0], 0, 0, 0);
            acc[i][1] = __builtin_amdgcn_mfma_f32_16x16x32_bf16(af[i], bc[1], acc[i][1], 0, 0, 0);
        }
#pragma unroll
        for (int i = 0; i < 4; ++i) {
            acc[i][0] = __builtin_amdgcn_mfma_f32_16x16x32_bf16(ag[i], bc[2], acc[i][0], 0, 0, 0);
            acc[i][1] = __builtin_amdgcn_mfma_f32_16x16x32_bf16(ag[i], bc[3], acc[i][1], 0, 0, 0);
        }
    };

    // ---- prologue ----
    float a00 = pA0[0], a01 = pA1[0]; advL();      // ph0 values, ptr->ph1
    float aN0 = pA0[0], aN1 = pA1[0]; advL();      // ph1 values, ptr->ph2
    stage(a00, a01, Al); advS();                   // stage ph0 -> buf0, s->ph1
    loadB(bEv);                                    // B ph0
    loadB(bOd);                                    // B ph1
    __syncthreads();

    const int np2 = nph >> 1;
    for (int p2 = 0; p2 < np2; ++p2) {
        const bool last = (p2 == np2 - 1);
        // ---- even phase (buf0) ----
        mma(Al, bEv);
        if (!last) loadB(bEv);                     // B ph+2
        stage(aN0, aN1, Al + 4096); advS();        // stage odd phase -> buf1
        if (!last) { aN0 = pA0[0]; aN1 = pA1[0]; advL(); }
        __syncthreads();
        // ---- odd phase (buf1) ----
        mma(Al + 4096, bOd);
        if (!last) {
            loadB(bOd);                            // B ph+3
            stage(aN0, aN1, Al); advS();           // stage next even -> buf0
            aN0 = pA0[0]; aN1 = pA1[0]; advL();
        }
        __syncthreads();
    }

    // ---- epilogue: C/D layout col=lane&15, row=(lane>>4)*4+reg ----
    const int mrow0 = m0 + ((lane >> 4) << 2);
    const int ncol = (wv << 5) + nib;
#pragma unroll
    for (int i = 0; i < 4; ++i)
#pragma unroll
        for (int j = 0; j < 2; ++j)
#pragma unroll
            for (int v = 0; v < 4; ++v) {
                int m = mrow0 + i * 16 + v;
                if (m < NN) Y[(size_t)m * 256 + ncol + j * 16] = (__bf16)acc[i][j][v];
            }
}

__global__ __launch_bounds__(512, 4) void mega_gemm1(const float* __restrict__ bondT,
                                                     const float* __restrict__ angleT,
                                                     const __bf16* __restrict__ Wp1b,
                                                     const __bf16* __restrict__ Wp1a,
                                                     __bf16* __restrict__ Yb,
                                                     __bf16* __restrict__ Ya1,
                                                     __bf16* __restrict__ Ya2) {
    __shared__ __align__(16) __bf16 Al[2 * 4096];
    int bx = blockIdx.x;
    if (bx < 314) {
        gemm1_body<0>(bondT, Wp1b, Yb, bx, Al, 0, 8);          // bond first
    } else {
        int ang = bx - 314;
        int half = ang & 1, mb = ang >> 1;   // even/odd interleave: partners share A lines
        gemm1_body<1>(angleT, Wp1a, half ? Ya2 : Ya1, mb, Al, half ? 24 : 0, 24);
    }
}

// ============================================================
// agg1: layer-1 aggregation, BOTH chains per wave. Single-readlane
// weight accumulation (R9-proven). Angle K-half partials (separate
// bf16 planes) merged inline. Output Hba channel-interleaved.
// ============================================================
__global__ __launch_bounds__(256) void agg1(const __bf16* __restrict__ Yb,
                                            const __bf16* __restrict__ Ya1,
                                            const __bf16* __restrict__ Ya2,
                                            const int* __restrict__ adj,
                                            const int* __restrict__ deg,
                                            const float* __restrict__ biasb,
                                            const float* __restrict__ biasa,
                                            __bf16* __restrict__ Hba) {
    int node = blockIdx.x * 4 + (threadIdx.x >> 6);
    int h = threadIdx.x & 63;
    if (node >= NN) return;
    int dg = min(deg[node], 64);
    int e = adj[(size_t)node * 64 + h];
    bool val = h < dg;
    int r = e >> 28;
    unsigned long long bl0 = __ballot(val && r == 0);
    unsigned long long bl1 = __ballot(val && r == 1);
    unsigned long long bl2 = __ballot(val && r == 2);
    int c0 = __popcll(bl0), c1 = __popcll(bl1), c2 = __popcll(bl2);
    float w = val ? 1.f / (float)((r == 0) ? c0 : (r == 1) ? c1 : c2) : 0.f;
    float sb = 0.f, sa = 0.f;
    if (dg > 0) {
        int e0 = __builtin_amdgcn_readfirstlane(e);
        int ec = val ? e : e0;
        for (int k0 = 0; k0 < dg; k0 += 16) {
            float vb[16], va[16];
#pragma unroll
            for (int i = 0; i < 16; ++i) {
                int ek = __builtin_amdgcn_readlane(ec, k0 + i);
                size_t base = (size_t)(ek & 0x0FFFFFFF) * 256 + (ek >> 28) * 64 + h;
                vb[i] = (float)Yb[base];
                va[i] = (float)Ya1[base] + (float)Ya2[base];
            }
#pragma unroll
            for (int i = 0; i < 16; ++i) {
                float wk = readlane_f(w, k0 + i);  // 0 beyond dg / invalid
                sb = fmaf(vb[i], wk, sb);
                sa = fmaf(va[i], wk, sa);
            }
        }
    }
    size_t ro = (size_t)node * 256 + 192 + h;
    float ob = (float)Yb[ro] + biasb[h] + sb;
    float oa = (float)Ya1[ro] + (float)Ya2[ro] + biasa[h] + sa;
    bf16x2 o;
    o[0] = (__bf16)fmaxf(ob, 0.f);
    o[1] = (__bf16)fmaxf(oa, 0.f);
    *(bf16x2*)(Hba + ((size_t)node * 64 + h) * 2) = o;
}

// ============================================================
// agg2mm: FUSED layer-2 aggregation + GEMM + pooling (R15-proven)
// + last-block-done FINAL reduction (deletes the final2 launch).
// ============================================================
__global__ __launch_bounds__(256) void agg2mm(const __bf16* __restrict__ Hba,
                                              const int* __restrict__ adj,
                                              const int* __restrict__ deg,
                                              const __bf16* __restrict__ Wpb,
                                              const __bf16* __restrict__ Wpa,
                                              const float* __restrict__ bb,
                                              const float* __restrict__ ba,
                                              const int* __restrict__ crys,
                                              float* __restrict__ pooled,
                                              int* __restrict__ done,
                                              const float* __restrict__ fcW,
                                              const float* __restrict__ fcb,
                                              float* __restrict__ out) {
    __shared__ __align__(16) __bf16 Xl[2][16][264];   // +8 pad: 2-way-free LDS stride
    __shared__ int lastFlag;
    const int tid = threadIdx.x, lane = tid & 63, wv = tid >> 6;
    const int node0 = blockIdx.x * 16;
    const int h = lane;

    // ---- phase 1: gather (4 nodes per wave) ----
    for (int s = 0; s < 4; ++s) {
        const int nl = wv * 4 + s;
        const int node = node0 + nl;
        float hb = 0.f, rb0 = 0.f, rb1 = 0.f, rb2 = 0.f;
        float ha = 0.f, ra0 = 0.f, ra1 = 0.f, ra2 = 0.f;
        if (node < NN) {
            int dg = min(deg[node], 64);
            int e = adj[(size_t)node * 64 + h];
            bool val = h < dg;
            int r = e >> 28;
            unsigned long long bl0 = __ballot(val && r == 0);
            unsigned long long bl1 = __ballot(val && r == 1);
            unsigned long long bl2 = __ballot(val && r == 2);
            int c0 = __popcll(bl0), c1 = __popcll(bl1), c2 = __popcll(bl2);
            float sb0 = 0.f, sb1 = 0.f, sb2 = 0.f;
            float sa0 = 0.f, sa1 = 0.f, sa2 = 0.f;
            bf16x2 hr = *(const bf16x2*)(Hba + ((size_t)node * 64 + h) * 2);
            hb = (float)hr[0];
            ha = (float)hr[1];
            if (dg > 0) {
                int e0 = __builtin_amdgcn_readfirstlane(e);
                int ec = val ? e : e0;
                for (int k0 = 0; k0 < dg; k0 += 16) {
                    float vb[16], va[16];
#pragma unroll
                    for (int i = 0; i < 16; ++i) {
                        int ek = __builtin_amdgcn_readlane(ec, k0 + i);
                        bf16x2 v2 = *(const bf16x2*)(Hba + (((size_t)(ek & 0x0FFFFFFF)) * 64 + h) * 2);
                        vb[i] = (float)v2[0];
                        va[i] = (float)v2[1];
                    }
#pragma unroll
                    for (int i = 0; i < 16; ++i) {
                        int kk = k0 + i;
                        if (kk < dg) {  // wave-uniform
                            int rr = __builtin_amdgcn_readlane(ec, kk) >> 28;
                            if (rr == 0)      { sb0 += vb[i]; sa0 += va[i]; }
                            else if (rr == 1) { sb1 += vb[i]; sa1 += va[i]; }
                            else              { sb2 += vb[i]; sa2 += va[i]; }
                        }
                    }
                }
            }
            float i0 = 1.f / fmaxf((float)c0, 1.f);
            float i1 = 1.f / fmaxf((float)c1, 1.f);
            float i2 = 1.f / fmaxf((float)c2, 1.f);
            rb0 = sb0 * i0; rb1 = sb1 * i1; rb2 = sb2 * i2;
            ra0 = sa0 * i0; ra1 = sa1 * i1; ra2 = sa2 * i2;
        }
        float vb4[4] = {hb, rb0, rb1, rb2};
        float va4[4] = {ha, ra0, ra1, ra2};
#pragma unroll
        for (int q = 0; q < 4; ++q) {
            Xl[0][nl][q * 64 + h] = (__bf16)vb4[q];
            Xl[1][nl][q * 64 + h] = (__bf16)va4[q];
        }
    }
    __syncthreads();

    // ---- phase 2: MFMA + pooling ----
    const int ch = wv >> 1, colh = wv & 1;
    const __bf16* Xc = &Xl[ch][0][0];
    const bf16x8* Bg = (const bf16x8*)(ch ? Wpa : Wpb);
    const float* bias = ch ? ba : bb;
    const int base = ch ? 64 : 0;
    const int k8b = lane >> 4, nib = lane & 15;
    f32x4 acc[2] = {};
#pragma unroll
    for (int kt = 0; kt < 8; ++kt) {
        bf16x8 a0 = *(const bf16x8*)&Xc[nib * 264 + kt * 32 + k8b * 8];
        bf16x8 b0 = Bg[(((size_t)kt * 4 + colh * 2 + 0) * 4 + k8b) * 16 + nib];
        bf16x8 b1 = Bg[(((size_t)kt * 4 + colh * 2 + 1) * 4 + k8b) * 16 + nib];
        acc[0] = __builtin_amdgcn_mfma_f32_16x16x32_bf16(a0, b0, acc[0], 0, 0, 0);
        acc[1] = __builtin_amdgcn_mfma_f32_16x16x32_bf16(a0, b1, acc[1], 0, 0, 0);
    }
    const int rowoff = ((lane >> 4) << 2);
#pragma unroll
    for (int v = 0; v < 4; ++v) {
        int m = node0 + rowoff + v;
        if (m < NN) {
            int cc = 0;
#pragma unroll
            for (int t = 1; t < NCRYS; ++t) cc += (m >= crys[t * 2]) ? 1 : 0;
            int sub = ((m >> 4) + ((m >> 2) & 3)) & (NSUB - 1);
            float* pb = &pooled[((size_t)cc * NSUB + sub) * 128 + base];
#pragma unroll
            for (int j = 0; j < 2; ++j) {
                int n = colh * 32 + j * 16 + nib;
                float o = fmaxf(acc[j][v] + bias[n], 0.f);
                atomicAdd(&pb[n], o);
            }
        }
    }

    // ---- last-block-done final reduction (bounded, no spin on producers) ----
    __threadfence();
    __syncthreads();
    if (tid == 0) lastFlag = (atomicAdd(done, 1) == gridDim.x - 1) ? 1 : 0;
    __syncthreads();
    if (lastFlag) {
        __threadfence();   // acquire: all other blocks' atomics visible
        // 40 outputs: wave wv handles go = wv, wv+4, ..., wv+36
        for (int go = wv; go < NCRYS * 2; go += 4) {
            int c = go >> 1, o = go & 1;
            float cnt = (float)(crys[c * 2 + 1] - crys[c * 2]);
            float sb = 0.f, sa = 0.f;
            for (int s = 0; s < NSUB; ++s) {
                sb += pooled[((size_t)c * NSUB + s) * 128 + lane];
                sa += pooled[((size_t)c * NSUB + s) * 128 + 64 + lane];
            }
            float a = sb * fcW[lane * 2 + o] + sa * fcW[(64 + lane) * 2 + o];
            for (int s = 32; s > 0; s >>= 1) a += __shfl_down(a, s);
            if (lane == 0) out[c * 2 + o] = a / cnt + fcb[o];
        }
    }
}

extern "C" void kernel_launch(void* const* d_in, const int* in_sizes, int n_in,
                              void* d_out, int out_size, void* d_ws, size_t ws_size,
                              hipStream_t stream) {
    const float* bond    = (const float*)d_in[0];
    const float* angle   = (const float*)d_in[1];
    const int*   species = (const int*)d_in[2];
    const int*   nbr     = (const int*)d_in[3];
    const int*   crys    = (const int*)d_in[4];
    const float* W1b_rel = (const float*)d_in[5];
    const float* W1b_root= (const float*)d_in[6];
    const float* b1b     = (const float*)d_in[7];
    const float* W1a_rel = (const float*)d_in[8];
    const float* W1a_root= (const float*)d_in[9];
    const float* b1a     = (const float*)d_in[10];
    const float* W2b_rel = (const float*)d_in[11];
    const float* W2b_root= (const float*)d_in[12];
    const float* b2b     = (const float*)d_in[13];
    const float* W2a_rel = (const float*)d_in[14];
    const float* W2a_root= (const float*)d_in[15];
    const float* b2a     = (const float*)d_in[16];
    const float* fcW     = (const float*)d_in[17];
    const float* fcb     = (const float*)d_in[18];
    float* out = (float*)d_out;

    char* ws = (char*)d_ws;
    size_t off = 0;
    auto alloc = [&](size_t bytes) {
        char* p = ws + off;
        off = (off + bytes + 255) & ~(size_t)255;
        return p;
    };
    __bf16* Wp1b = (__bf16*)alloc((size_t)512 * 256 * 2);    // K padded 480->512
    __bf16* Wp1a = (__bf16*)alloc((size_t)3072 * 256 * 2);   // K padded 2880->3072
    __bf16* Wp2b = (__bf16*)alloc((size_t)256 * 64 * 2);     // concat layout
    __bf16* Wp2a = (__bf16*)alloc((size_t)256 * 64 * 2);
    float*  bondT = (float*)alloc((size_t)16 * NNP * 4);     // rows padded 12->16
    float*  angleT= (float*)alloc((size_t)156 * NNP * 4);    // rows padded 144->156
    __bf16* Yb   = (__bf16*)alloc((size_t)NN * 256 * 2);     // bond pre-agg (bf16)
    __bf16* Ya1  = (__bf16*)alloc((size_t)NN * 256 * 2);     // angle K-half partials (bf16)
    __bf16* Ya2  = (__bf16*)alloc((size_t)NN * 256 * 2);
    __bf16* Hba  = (__bf16*)alloc((size_t)NNP * 64 * 2 * 2); // H, b/a interleaved
    int*    adj  = (int*)alloc((size_t)NN * 64 * 4);
    int*    deg  = (int*)alloc((size_t)(NN + 64) * 4);       // deg + done counter
    int*    done = deg + NN;
    float*  pooled = (float*)alloc((size_t)NCRYS * NSUB * 128 * 4);

    hipMemsetAsync(deg, 0, (size_t)(NN + 64) * 4, stream);

    setup_kernel<<<1823, 256, 0, stream>>>(species, nbr, adj, deg,
                                           W1b_rel, W1b_root, W1a_rel, W1a_root,
                                           W2b_rel, W2b_root, W2a_rel, W2a_root,
                                           Wp1b, Wp1a, Wp2b, Wp2a,
                                           bond, angle, bondT, angleT, pooled);

    mega_gemm1<<<942, 512, 0, stream>>>(bondT, angleT, Wp1b, Wp1a, Yb, Ya1, Ya2);
    agg1<<<5000, 256, 0, stream>>>(Yb, Ya1, Ya2, adj, deg, b1b, b1a, Hba);
    agg2mm<<<1256, 256, 0, stream>>>(Hba, adj, deg, Wp2b, Wp2a, b2b, b2a, crys,
                                     pooled, done, fcW, fcb, out);
}

// Round 18
// 208.638 us; speedup vs baseline: 1.4090x; 1.4090x over previous
//
#include <hip/hip_runtime.h>

#define NN 20000
#define NNP 20096       // padded rows: 314*64
#define NEIGH 12
#define NCRYS 20
#define NSUB 16         // pooled partial-sum split

typedef __bf16 bf16x8 __attribute__((ext_vector_type(8)));
typedef __bf16 bf16x4 __attribute__((ext_vector_type(4)));
typedef __bf16 bf16x2 __attribute__((ext_vector_type(2)));
typedef float f32x4 __attribute__((ext_vector_type(4)));

__device__ __forceinline__ float readlane_f(float v, int l) {
    return __int_as_float(__builtin_amdgcn_readlane(__float_as_int(v), l));
}

// ============================================================
// pack8: one thread -> one contiguous bf16x8 chunk of Wp (8 k's, one n).
// Writes fully coalesced. Layer-1 layout (N=256): Wp[kt][nt][k8][ni][j]
// ============================================================
__device__ __forceinline__ void pack8(const float* Wrel, const float* Wroot,
                                      __bf16* Wp, int K, int t) {
    int n = t & 255, kq = t >> 8;          // kq = kt*4 + k8
    int kt = kq >> 2, k8 = kq & 3;
    int r = n >> 6, h = n & 63;
    int k0 = kt * 32 + k8 * 8;
    const float* src = (r < 3) ? (Wrel + ((size_t)r * K + k0) * 64 + h)
                               : (Wroot + (size_t)k0 * 64 + h);
    bf16x8 v;
#pragma unroll
    for (int j = 0; j < 8; ++j) v[j] = (__bf16)src[(size_t)j * 64];
    size_t off = (((((size_t)kt * 16 + (n >> 4)) * 4 + k8) * 16) + (n & 15)) * 8;
    *(bf16x8*)&Wp[off] = v;
}

// layer-2 concat (K=256, N=64): rows 0-63 W_root, 64+64q.. W_rel[q]
__device__ __forceinline__ void pack_cat8(const float* Wrel, const float* Wroot,
                                          __bf16* Wp, int t) {
    int n = t & 63, kq = t >> 6;           // kq = kt*4 + k8 (kt 0..7)
    int kt = kq >> 2, k8 = kq & 3;
    int k0 = kt * 32 + k8 * 8;             // 8-aligned, never crosses 64-block
    int q = k0 >> 6, kk = k0 & 63;
    const float* src = q ? (Wrel + (((size_t)(q - 1) * 64 + kk) * 64) + n)
                         : (Wroot + (size_t)kk * 64 + n);
    bf16x8 v;
#pragma unroll
    for (int j = 0; j < 8; ++j) v[j] = (__bf16)src[(size_t)j * 64];
    size_t off = (((((size_t)kt * 4 + (n >> 4)) * 4 + k8) * 16) + (n & 15)) * 8;
    *(bf16x8*)&Wp[off] = v;
}

// ============================================================
// setup: HEAVY-FIRST block order to trim the tail:
//   [0,628)    transpose (heaviest per block)
//   [628,884)  weight pack (medium)
//   [884,1822) adj build (light)
//   1822       pooled zero (replaces a memset dispatch)
// ============================================================
__global__ __launch_bounds__(256) void setup_kernel(
    const int* __restrict__ species, const int* __restrict__ nbr,
    int* __restrict__ adj, int* __restrict__ deg,
    const float* __restrict__ W1b_rel, const float* __restrict__ W1b_root,
    const float* __restrict__ W1a_rel, const float* __restrict__ W1a_root,
    const float* __restrict__ W2b_rel, const float* __restrict__ W2b_root,
    const float* __restrict__ W2a_rel, const float* __restrict__ W2a_root,
    __bf16* __restrict__ Wp1b, __bf16* __restrict__ Wp1a,
    __bf16* __restrict__ Wp2b, __bf16* __restrict__ Wp2a,
    const float* __restrict__ bond, const float* __restrict__ angle,
    float* __restrict__ bondT, float* __restrict__ angleT,
    float* __restrict__ pooled) {
    __shared__ float ls[64 * 145];
    const int bx = blockIdx.x, tid = threadIdx.x;
    if (bx < 628) {
        int tb = bx;
        if (tb < 314) {
            int m0 = tb * 64;
            for (int idx = tid; idx < 64 * 144; idx += 256) {
                int mm = idx / 144, j = idx - mm * 144;
                int m = m0 + mm;
                ls[mm * 145 + j] = (m < NN) ? angle[(size_t)m * 144 + j] : 0.f;
            }
            __syncthreads();
            for (int idx = tid; idx < 156 * 64; idx += 256) {
                int j = idx >> 6, mm = idx & 63;
                angleT[(size_t)j * NNP + m0 + mm] = (j < 144) ? ls[mm * 145 + j] : 0.f;
            }
        } else {
            int m0 = (tb - 314) * 64;
            for (int idx = tid; idx < 64 * 12; idx += 256) {
                int mm = idx / 12, j = idx - mm * 12;
                int m = m0 + mm;
                ls[mm * 13 + j] = (m < NN) ? bond[(size_t)m * 12 + j] : 0.f;
            }
            __syncthreads();
            for (int idx = tid; idx < 16 * 64; idx += 256) {
                int j = idx >> 6, mm = idx & 63;
                bondT[(size_t)j * NNP + m0 + mm] = (j < 12) ? ls[mm * 13 + j] : 0.f;
            }
        }
    } else if (bx < 884) {
        const int S0 = 15360;               // Wp1b pack8 (kt 0..14, K=480)
        const int S1 = S0 + 92160;          // Wp1a pack8 (kt 0..89, K=2880)
        const int S2 = S1 + 2048;           // Wp2b pack_cat8
        const int S3 = S2 + 2048;           // Wp2a pack_cat8
        const int S4 = S3 + 8192;           // Wp1b zero tail (k 480..511)
        const int S5 = S4 + 49152;          // Wp1a zero tail (k 2880..3071)
        for (int idx = (bx - 628) * 256 + tid; idx < S5; idx += 256 * 256) {
            if (idx < S0)       pack8(W1b_rel, W1b_root, Wp1b, 480, idx);
            else if (idx < S1)  pack8(W1a_rel, W1a_root, Wp1a, 2880, idx - S0);
            else if (idx < S2)  pack_cat8(W2b_rel, W2b_root, Wp2b, idx - S1);
            else if (idx < S3)  pack_cat8(W2a_rel, W2a_root, Wp2a, idx - S2);
            else if (idx < S4)  Wp1b[480 * 256 + (idx - S3)] = (__bf16)0.f;
            else                Wp1a[2880 * 256 + (idx - S4)] = (__bf16)0.f;
        }
    } else if (bx < 1822) {
        int e = (bx - 884) * 256 + tid;
        if (e < NN * NEIGH) {
            int i = e / NEIGH;
            int d = nbr[e];
            int r = species[i] + species[d];
            int slot = atomicAdd(&deg[d], 1);
            if (slot < 64) adj[(size_t)d * 64 + slot] = i | (r << 28);
        }
    } else {
        for (int i = tid; i < NCRYS * NSUB * 128; i += 256) pooled[i] = 0.f;
    }
}

// ============================================================
// gemm1: 64x256 tile, 512 threads (8 waves, each 64r x 32c, acc[4][2]).
// Proven R5 structure: 64-K phases in [ph0, ph0+nph), x2 unrolled loop,
// depth-2 B reg-prefetch, incremental pointers, LDS A ping-pong.
// Angle K-split x2: halves even/odd-interleaved in dispatch (partners
// share angleT read lines), outputs to SEPARATE bf16 planes.
// Bond blocks dispatched FIRST so the tail is uniform 24-phase blocks.
// ============================================================
template <int MODE>  // 0: bond KPAD=512 DIVN=40; 1: angle KPAD=3072 DIVN=20
__device__ __forceinline__ void gemm1_body(const float* __restrict__ xT,
                                           const __bf16* __restrict__ Wp,
                                           __bf16* __restrict__ Y, int mb,
                                           __bf16* __restrict__ Al,
                                           int ph0, int nph) {
    constexpr int DIVN = (MODE == 0) ? 40 : 20;
    constexpr int ADDJ = 64 / DIVN;          // 1 / 3
    constexpr int ADDS = 64 % DIVN;          // 24 / 4
    constexpr float F0 = (MODE == 0) ? 0.f : -1.f;
    constexpr float FS = (MODE == 0) ? (8.f / 39.f) : (2.f / 19.f);
    constexpr float NG2 = ((MODE == 0) ? -25.f : -100.f) * 1.44269504f;  // -gamma^-2*log2e
    const float C  = __builtin_amdgcn_exp2f(2.f * NG2 * FS * FS);
    const float P1 = NG2 * FS * FS;
    const float P2 = -2.f * NG2 * FS;

    const int tid = threadIdx.x;
    const int lane = tid & 63, wv = tid >> 6;
    const int m0 = mb * 64;
    const int smt = tid >> 7;             // 0..3
    const int sk8 = (tid >> 5) & 3;
    const int smi = (tid >> 1) & 15;
    const int sjh = (tid & 1) * 4;
    const int sgm = m0 + smt * 16 + smi;
    const int kk0 = sk8 * 8 + sjh;        // k-offset within 32-tile, 0..28
    const int swoff = (((smt * 4 + sk8) * 16 + smi) * 8 + sjh);
    const int k8b = lane >> 4, nib = lane & 15;

    f32x4 acc[4][2] = {};

    const int k00 = ph0 * 64 + kk0;
    const int k01 = ph0 * 64 + 32 + kk0;
    const float* pA0 = xT + (size_t)(k00 / DIVN) * NNP + sgm;
    const float* pA1 = xT + (size_t)(k01 / DIVN) * NNP + sgm;
    int sL0 = k00 % DIVN, sL1 = k01 % DIVN;
    int sS0 = sL0, sS1 = sL1;

    const bf16x8* pB0 = (const bf16x8*)Wp + (size_t)ph0 * 2048 +
                        ((size_t)(2 * wv) * 4 + k8b) * 16 + nib;
    const bf16x8* pB1 = pB0 + 1024;

    bf16x8 bEv[4], bOd[4];

    auto advL = [&]() {
        sL0 += ADDS;
        if (sL0 >= DIVN) { sL0 -= DIVN; pA0 += (size_t)(ADDJ + 1) * NNP; } else pA0 += (size_t)ADDJ * NNP;
        sL1 += ADDS;
        if (sL1 >= DIVN) { sL1 -= DIVN; pA1 += (size_t)(ADDJ + 1) * NNP; } else pA1 += (size_t)ADDJ * NNP;
    };
    auto advS = [&]() {
        sS0 += ADDS; if (sS0 >= DIVN) sS0 -= DIVN;
        sS1 += ADDS; if (sS1 >= DIVN) sS1 -= DIVN;
    };
    auto loadB = [&](bf16x8* d) {
        d[0] = pB0[0]; d[1] = pB0[64]; d[2] = pB1[0]; d[3] = pB1[64];
        pB0 += 2048; pB1 += 2048;
    };
    auto stage = [&](float a0, float a1, __bf16* dst) {
        float d0 = a0 - (F0 + (float)sS0 * FS);
        float d1 = a1 - (F0 + (float)sS1 * FS);
        float e0a = __builtin_amdgcn_exp2f(NG2 * d0 * d0);
        float q0a = __builtin_amdgcn_exp2f(fmaf(P2, d0, P1));
        float e0b = __builtin_amdgcn_exp2f(NG2 * d1 * d1);
        float q0b = __builtin_amdgcn_exp2f(fmaf(P2, d1, P1));
        float e1a = e0a * q0a, q1a = q0a * C;
        float e2a = e1a * q1a, e3a = e2a * q1a * C;
        float e1b = e0b * q0b, q1b = q0b * C;
        float e2b = e1b * q1b, e3b = e2b * q1b * C;
        bf16x4 v0, v1;
        v0[0] = (__bf16)e0a; v0[1] = (__bf16)e1a; v0[2] = (__bf16)e2a; v0[3] = (__bf16)e3a;
        v1[0] = (__bf16)e0b; v1[1] = (__bf16)e1b; v1[2] = (__bf16)e2b; v1[3] = (__bf16)e3b;
        *(bf16x4*)&dst[swoff] = v0;
        *(bf16x4*)&dst[2048 + swoff] = v1;
    };
    auto mma = [&](const __bf16* Ab, const bf16x8* bc) {
        bf16x8 af[4], ag[4];
#pragma unroll
        for (int t4 = 0; t4 < 4; ++t4) {
            af[t4] = *(const bf16x8*)&Ab[(((((t4 << 2) + k8b) << 4) + nib) << 3)];
            ag[t4] = *(const bf16x8*)&Ab[2048 + (((((t4 << 2) + k8b) << 4) + nib) << 3)];
        }
#pragma unroll
        for (int i = 0; i < 4; ++i) {
            acc[i][0] = __builtin_amdgcn_mfma_f32_16x16x32_bf16(af[i], bc[0], acc[i][0], 0, 0, 0);
            acc[i][1] = __builtin_amdgcn_mfma_f32_16x16x32_bf16(af[i], bc[1], acc[i][1], 0, 0, 0);
        }
#pragma unroll
        for (int i = 0; i < 4; ++i) {
            acc[i][0] = __builtin_amdgcn_mfma_f32_16x16x32_bf16(ag[i], bc[2], acc[i][0], 0, 0, 0);
            acc[i][1] = __builtin_amdgcn_mfma_f32_16x16x32_bf16(ag[i], bc[3], acc[i][1], 0, 0, 0);
        }
    };

    // ---- prologue ----
    float a00 = pA0[0], a01 = pA1[0]; advL();      // ph0 values, ptr->ph1
    float aN0 = pA0[0], aN1 = pA1[0]; advL();      // ph1 values, ptr->ph2
    stage(a00, a01, Al); advS();                   // stage ph0 -> buf0, s->ph1
    loadB(bEv);                                    // B ph0
    loadB(bOd);                                    // B ph1
    __syncthreads();

    const int np2 = nph >> 1;
    for (int p2 = 0; p2 < np2; ++p2) {
        const bool last = (p2 == np2 - 1);
        // ---- even phase (buf0) ----
        mma(Al, bEv);
        if (!last) loadB(bEv);                     // B ph+2
        stage(aN0, aN1, Al + 4096); advS();        // stage odd phase -> buf1
        if (!last) { aN0 = pA0[0]; aN1 = pA1[0]; advL(); }
        __syncthreads();
        // ---- odd phase (buf1) ----
        mma(Al + 4096, bOd);
        if (!last) {
            loadB(bOd);                            // B ph+3
            stage(aN0, aN1, Al); advS();           // stage next even -> buf0
            aN0 = pA0[0]; aN1 = pA1[0]; advL();
        }
        __syncthreads();
    }

    // ---- epilogue: C/D layout col=lane&15, row=(lane>>4)*4+reg ----
    const int mrow0 = m0 + ((lane >> 4) << 2);
    const int ncol = (wv << 5) + nib;
#pragma unroll
    for (int i = 0; i < 4; ++i)
#pragma unroll
        for (int j = 0; j < 2; ++j)
#pragma unroll
            for (int v = 0; v < 4; ++v) {
                int m = mrow0 + i * 16 + v;
                if (m < NN) Y[(size_t)m * 256 + ncol + j * 16] = (__bf16)acc[i][j][v];
            }
}

__global__ __launch_bounds__(512, 4) void mega_gemm1(const float* __restrict__ bondT,
                                                     const float* __restrict__ angleT,
                                                     const __bf16* __restrict__ Wp1b,
                                                     const __bf16* __restrict__ Wp1a,
                                                     __bf16* __restrict__ Yb,
                                                     __bf16* __restrict__ Ya1,
                                                     __bf16* __restrict__ Ya2) {
    __shared__ __align__(16) __bf16 Al[2 * 4096];
    int bx = blockIdx.x;
    if (bx < 314) {
        gemm1_body<0>(bondT, Wp1b, Yb, bx, Al, 0, 8);          // bond first
    } else {
        int ang = bx - 314;
        int half = ang & 1, mb = ang >> 1;   // even/odd interleave: partners share A lines
        gemm1_body<1>(angleT, Wp1a, half ? Ya2 : Ya1, mb, Al, half ? 24 : 0, 24);
    }
}

// ============================================================
// agg1: layer-1 aggregation, BOTH chains per wave. Single-readlane
// weight accumulation (R9-proven). Angle K-half partials (separate
// bf16 planes) merged inline. Output Hba channel-interleaved.
// ============================================================
__global__ __launch_bounds__(256) void agg1(const __bf16* __restrict__ Yb,
                                            const __bf16* __restrict__ Ya1,
                                            const __bf16* __restrict__ Ya2,
                                            const int* __restrict__ adj,
                                            const int* __restrict__ deg,
                                            const float* __restrict__ biasb,
                                            const float* __restrict__ biasa,
                                            __bf16* __restrict__ Hba) {
    int node = blockIdx.x * 4 + (threadIdx.x >> 6);
    int h = threadIdx.x & 63;
    if (node >= NN) return;
    int dg = min(deg[node], 64);
    int e = adj[(size_t)node * 64 + h];
    bool val = h < dg;
    int r = e >> 28;
    unsigned long long bl0 = __ballot(val && r == 0);
    unsigned long long bl1 = __ballot(val && r == 1);
    unsigned long long bl2 = __ballot(val && r == 2);
    int c0 = __popcll(bl0), c1 = __popcll(bl1), c2 = __popcll(bl2);
    float w = val ? 1.f / (float)((r == 0) ? c0 : (r == 1) ? c1 : c2) : 0.f;
    float sb = 0.f, sa = 0.f;
    if (dg > 0) {
        int e0 = __builtin_amdgcn_readfirstlane(e);
        int ec = val ? e : e0;
        for (int k0 = 0; k0 < dg; k0 += 16) {
            float vb[16], va[16];
#pragma unroll
            for (int i = 0; i < 16; ++i) {
                int ek = __builtin_amdgcn_readlane(ec, k0 + i);
                size_t base = (size_t)(ek & 0x0FFFFFFF) * 256 + (ek >> 28) * 64 + h;
                vb[i] = (float)Yb[base];
                va[i] = (float)Ya1[base] + (float)Ya2[base];
            }
#pragma unroll
            for (int i = 0; i < 16; ++i) {
                float wk = readlane_f(w, k0 + i);  // 0 beyond dg / invalid
                sb = fmaf(vb[i], wk, sb);
                sa = fmaf(va[i], wk, sa);
            }
        }
    }
    size_t ro = (size_t)node * 256 + 192 + h;
    float ob = (float)Yb[ro] + biasb[h] + sb;
    float oa = (float)Ya1[ro] + (float)Ya2[ro] + biasa[h] + sa;
    bf16x2 o;
    o[0] = (__bf16)fmaxf(ob, 0.f);
    o[1] = (__bf16)fmaxf(oa, 0.f);
    *(bf16x2*)(Hba + ((size_t)node * 64 + h) * 2) = o;
}

// ============================================================
// agg2mm: FUSED layer-2 aggregation + GEMM + pooling (R15-proven).
// NO device-scope fence / done-counter (R17 lesson: per-block
// __threadfence forces L2 writeback on non-coherent XCDs -> 2.5x slowdown).
// ============================================================
__global__ __launch_bounds__(256) void agg2mm(const __bf16* __restrict__ Hba,
                                              const int* __restrict__ adj,
                                              const int* __restrict__ deg,
                                              const __bf16* __restrict__ Wpb,
                                              const __bf16* __restrict__ Wpa,
                                              const float* __restrict__ bb,
                                              const float* __restrict__ ba,
                                              const int* __restrict__ crys,
                                              float* __restrict__ pooled) {
    __shared__ __align__(16) __bf16 Xl[2][16][264];   // +8 pad: 2-way-free LDS stride
    const int tid = threadIdx.x, lane = tid & 63, wv = tid >> 6;
    const int node0 = blockIdx.x * 16;
    const int h = lane;

    // ---- phase 1: gather (4 nodes per wave) ----
    for (int s = 0; s < 4; ++s) {
        const int nl = wv * 4 + s;
        const int node = node0 + nl;
        float hb = 0.f, rb0 = 0.f, rb1 = 0.f, rb2 = 0.f;
        float ha = 0.f, ra0 = 0.f, ra1 = 0.f, ra2 = 0.f;
        if (node < NN) {
            int dg = min(deg[node], 64);
            int e = adj[(size_t)node * 64 + h];
            bool val = h < dg;
            int r = e >> 28;
            unsigned long long bl0 = __ballot(val && r == 0);
            unsigned long long bl1 = __ballot(val && r == 1);
            unsigned long long bl2 = __ballot(val && r == 2);
            int c0 = __popcll(bl0), c1 = __popcll(bl1), c2 = __popcll(bl2);
            float sb0 = 0.f, sb1 = 0.f, sb2 = 0.f;
            float sa0 = 0.f, sa1 = 0.f, sa2 = 0.f;
            bf16x2 hr = *(const bf16x2*)(Hba + ((size_t)node * 64 + h) * 2);
            hb = (float)hr[0];
            ha = (float)hr[1];
            if (dg > 0) {
                int e0 = __builtin_amdgcn_readfirstlane(e);
                int ec = val ? e : e0;
                for (int k0 = 0; k0 < dg; k0 += 16) {
                    float vb[16], va[16];
#pragma unroll
                    for (int i = 0; i < 16; ++i) {
                        int ek = __builtin_amdgcn_readlane(ec, k0 + i);
                        bf16x2 v2 = *(const bf16x2*)(Hba + (((size_t)(ek & 0x0FFFFFFF)) * 64 + h) * 2);
                        vb[i] = (float)v2[0];
                        va[i] = (float)v2[1];
                    }
#pragma unroll
                    for (int i = 0; i < 16; ++i) {
                        int kk = k0 + i;
                        if (kk < dg) {  // wave-uniform
                            int rr = __builtin_amdgcn_readlane(ec, kk) >> 28;
                            if (rr == 0)      { sb0 += vb[i]; sa0 += va[i]; }
                            else if (rr == 1) { sb1 += vb[i]; sa1 += va[i]; }
                            else              { sb2 += vb[i]; sa2 += va[i]; }
                        }
                    }
                }
            }
            float i0 = 1.f / fmaxf((float)c0, 1.f);
            float i1 = 1.f / fmaxf((float)c1, 1.f);
            float i2 = 1.f / fmaxf((float)c2, 1.f);
            rb0 = sb0 * i0; rb1 = sb1 * i1; rb2 = sb2 * i2;
            ra0 = sa0 * i0; ra1 = sa1 * i1; ra2 = sa2 * i2;
        }
        float vb4[4] = {hb, rb0, rb1, rb2};
        float va4[4] = {ha, ra0, ra1, ra2};
#pragma unroll
        for (int q = 0; q < 4; ++q) {
            Xl[0][nl][q * 64 + h] = (__bf16)vb4[q];
            Xl[1][nl][q * 64 + h] = (__bf16)va4[q];
        }
    }
    __syncthreads();

    // ---- phase 2: MFMA + pooling ----
    const int ch = wv >> 1, colh = wv & 1;
    const __bf16* Xc = &Xl[ch][0][0];
    const bf16x8* Bg = (const bf16x8*)(ch ? Wpa : Wpb);
    const float* bias = ch ? ba : bb;
    const int base = ch ? 64 : 0;
    const int k8b = lane >> 4, nib = lane & 15;
    f32x4 acc[2] = {};
#pragma unroll
    for (int kt = 0; kt < 8; ++kt) {
        bf16x8 a0 = *(const bf16x8*)&Xc[nib * 264 + kt * 32 + k8b * 8];
        bf16x8 b0 = Bg[(((size_t)kt * 4 + colh * 2 + 0) * 4 + k8b) * 16 + nib];
        bf16x8 b1 = Bg[(((size_t)kt * 4 + colh * 2 + 1) * 4 + k8b) * 16 + nib];
        acc[0] = __builtin_amdgcn_mfma_f32_16x16x32_bf16(a0, b0, acc[0], 0, 0, 0);
        acc[1] = __builtin_amdgcn_mfma_f32_16x16x32_bf16(a0, b1, acc[1], 0, 0, 0);
    }
    const int rowoff = ((lane >> 4) << 2);
#pragma unroll
    for (int v = 0; v < 4; ++v) {
        int m = node0 + rowoff + v;
        if (m < NN) {
            int cc = 0;
#pragma unroll
            for (int t = 1; t < NCRYS; ++t) cc += (m >= crys[t * 2]) ? 1 : 0;
            int sub = ((m >> 4) + ((m >> 2) & 3)) & (NSUB - 1);
            float* pb = &pooled[((size_t)cc * NSUB + sub) * 128 + base];
#pragma unroll
            for (int j = 0; j < 2; ++j) {
                int n = colh * 32 + j * 16 + nib;
                float o = fmaxf(acc[j][v] + bias[n], 0.f);
                atomicAdd(&pb[n], o);
            }
        }
    }
}

// ============================================================
// final: reduce partials, divide by count, FC
// ============================================================
__global__ void final2(const float* __restrict__ pooled, const int* __restrict__ crys,
                       const float* __restrict__ fcW, const float* __restrict__ fcb,
                       float* __restrict__ out) {
    int c = blockIdx.x >> 1, o = blockIdx.x & 1;
    int l = threadIdx.x;  // 0..63
    float cnt = (float)(crys[c * 2 + 1] - crys[c * 2]);
    float sb = 0.f, sa = 0.f;
    for (int s = 0; s < NSUB; ++s) {
        sb += pooled[((size_t)c * NSUB + s) * 128 + l];
        sa += pooled[((size_t)c * NSUB + s) * 128 + 64 + l];
    }
    float a = sb * fcW[l * 2 + o] + sa * fcW[(64 + l) * 2 + o];
    for (int s = 32; s > 0; s >>= 1) a += __shfl_down(a, s);
    if (l == 0) out[c * 2 + o] = a / cnt + fcb[o];
}

extern "C" void kernel_launch(void* const* d_in, const int* in_sizes, int n_in,
                              void* d_out, int out_size, void* d_ws, size_t ws_size,
                              hipStream_t stream) {
    const float* bond    = (const float*)d_in[0];
    const float* angle   = (const float*)d_in[1];
    const int*   species = (const int*)d_in[2];
    const int*   nbr     = (const int*)d_in[3];
    const int*   crys    = (const int*)d_in[4];
    const float* W1b_rel = (const float*)d_in[5];
    const float* W1b_root= (const float*)d_in[6];
    const float* b1b     = (const float*)d_in[7];
    const float* W1a_rel = (const float*)d_in[8];
    const float* W1a_root= (const float*)d_in[9];
    const float* b1a     = (const float*)d_in[10];
    const float* W2b_rel = (const float*)d_in[11];
    const float* W2b_root= (const float*)d_in[12];
    const float* b2b     = (const float*)d_in[13];
    const float* W2a_rel = (const float*)d_in[14];
    const float* W2a_root= (const float*)d_in[15];
    const float* b2a     = (const float*)d_in[16];
    const float* fcW     = (const float*)d_in[17];
    const float* fcb     = (const float*)d_in[18];
    float* out = (float*)d_out;

    char* ws = (char*)d_ws;
    size_t off = 0;
    auto alloc = [&](size_t bytes) {
        char* p = ws + off;
        off = (off + bytes + 255) & ~(size_t)255;
        return p;
    };
    __bf16* Wp1b = (__bf16*)alloc((size_t)512 * 256 * 2);    // K padded 480->512
    __bf16* Wp1a = (__bf16*)alloc((size_t)3072 * 256 * 2);   // K padded 2880->3072
    __bf16* Wp2b = (__bf16*)alloc((size_t)256 * 64 * 2);     // concat layout
    __bf16* Wp2a = (__bf16*)alloc((size_t)256 * 64 * 2);
    float*  bondT = (float*)alloc((size_t)16 * NNP * 4);     // rows padded 12->16
    float*  angleT= (float*)alloc((size_t)156 * NNP * 4);    // rows padded 144->156
    __bf16* Yb   = (__bf16*)alloc((size_t)NN * 256 * 2);     // bond pre-agg (bf16)
    __bf16* Ya1  = (__bf16*)alloc((size_t)NN * 256 * 2);     // angle K-half partials (bf16)
    __bf16* Ya2  = (__bf16*)alloc((size_t)NN * 256 * 2);
    __bf16* Hba  = (__bf16*)alloc((size_t)NNP * 64 * 2 * 2); // H, b/a interleaved
    int*    adj  = (int*)alloc((size_t)NN * 64 * 4);
    int*    deg  = (int*)alloc((size_t)NN * 4);
    float*  pooled = (float*)alloc((size_t)NCRYS * NSUB * 128 * 4);

    hipMemsetAsync(deg, 0, (size_t)NN * 4, stream);

    setup_kernel<<<1823, 256, 0, stream>>>(species, nbr, adj, deg,
                                           W1b_rel, W1b_root, W1a_rel, W1a_root,
                                           W2b_rel, W2b_root, W2a_rel, W2a_root,
                                           Wp1b, Wp1a, Wp2b, Wp2a,
                                           bond, angle, bondT, angleT, pooled);

    mega_gemm1<<<942, 512, 0, stream>>>(bondT, angleT, Wp1b, Wp1a, Yb, Ya1, Ya2);
    agg1<<<5000, 256, 0, stream>>>(Yb, Ya1, Ya2, adj, deg, b1b, b1a, Hba);
    agg2mm<<<1256, 256, 0, stream>>>(Hba, adj, deg, Wp2b, Wp2a, b2b, b2a, crys, pooled);
    final2<<<NCRYS * 2, 64, 0, stream>>>(pooled, crys, fcW, fcb, out);
}